// Round 2
// baseline (481.206 us; speedup 1.0000x reference)
//
#include <hip/hip_runtime.h>

// Elman RNN (relu), B=4096 T=4096 H=32, fp32 in/out.
// h_new[j] = relu( sum_k W_hh[j,k] h[k] + x*W_ih[j] + b_ih[j]+b_hh[j] )
//
// R11: width model from R9->R10 delta: VALU issue cyc ~ sum of instr widths;
// v_pk_fma_f32 = 4 cyc (2 ALU passes, saved NOTHING vs 2 scalar fma).
// C-build (4 pk_fma = 16 cyc) was 44% of per-step VALU while the matrix
// pipe sat at 14%. This round offloads C = x*W_ih + bias to MFMA:
//   c1 = mfma(Ax1, xfrag, cbias1)  — Ax col0 = W_ih (f16), xfrag = x at
//   k=0 only (f16), bias stays EXACT f32 in the C operand.
// Per-step prep VALU: 1 cvt_f16_f32 + 1 v_and (4 cyc) vs 16 cyc before.
// The x-MFMAs are independent of the recurrence (x prefetched 8 steps
// ahead) -> they fill the ~30% stall window. 4 rotating xfrag quads avoid
// WAR/RAW hazard nops (cvt/and batch issued >=3 instrs before the mfmas).
//
// MFMA mapping (unchanged): A1 row m computes unit u1(m)=8*(m>>2)+(m&3);
// A2 row m -> u1(m)+4. Lane (n=lane&15, quad q) exits with units 8q..8q+7
// = next B fragment, zero cross-lane transform. Ax1/Ax2 use the SAME row
// permutation so c lands in the same (reg,lane) slots as d.
// 256 blocks x 64 thr = 1 wave/CU, 16 batches per wave.

#define HSZ 32

typedef _Float16 half8 __attribute__((ext_vector_type(8)));
typedef _Float16 h2n __attribute__((ext_vector_type(2)));
typedef __fp16 fp16x2 __attribute__((ext_vector_type(2)));
typedef float f32x4 __attribute__((ext_vector_type(4)));
typedef unsigned uint4v __attribute__((ext_vector_type(4)));

// relu on a packed f16 pair: v_pk_max_f16 with inline 0.
static __device__ __forceinline__ fp16x2 relu_pk(fp16x2 a) {
  union {
    fp16x2 r;
    h2n n;
  } u;
  u.r = a;
  h2n z = {(_Float16)0.f, (_Float16)0.f};
  u.n = __builtin_elementwise_max(u.n, z);
  return u.r;
}

__global__ __attribute__((amdgpu_flat_work_group_size(64, 64),
                          amdgpu_waves_per_eu(1, 1)))
void rnn_reg_kernel(
    const float* __restrict__ x, const float* __restrict__ h_init,
    const float* __restrict__ W_ih, const float* __restrict__ W_hh,
    const float* __restrict__ b_ih, const float* __restrict__ b_hh,
    const float* __restrict__ W_reg, const float* __restrict__ b_reg,
    float* __restrict__ out, int T) {
  const int lane = threadIdx.x;             // 0..63
  const int lo4  = lane & 15;               // batch column n / A row m
  const int q    = lane >> 4;               // quad 0..3
  const int bg   = blockIdx.x * 16 + lo4;   // this lane's batch

  // Permuted A rows: row m of A1 is W_hh[u1(m)], row m of A2 is W_hh[u1(m)+4]
  const int u1m = 8 * (lo4 >> 2) + (lo4 & 3);
  half8 A1, A2;
#pragma unroll
  for (int j = 0; j < 8; ++j) {
    A1[j] = (_Float16)W_hh[u1m * HSZ + 8 * q + j];          // v_cvt_f16_f32 RNE
    A2[j] = (_Float16)W_hh[(u1m + 4) * HSZ + 8 * q + j];
  }

  // Ax fragments: column k=0 holds W_ih[u1(m)] (resp. +4), all else 0.
  // Lane (m=lo4, q) holds cols 8q..8q+7 -> only q==0 lanes carry col 0.
  half8 Ax1 = {}, Ax2 = {};
  if (q == 0) {
    Ax1[0] = (_Float16)W_ih[u1m];
    Ax2[0] = (_Float16)W_ih[u1m + 4];
  }

  // Exact f32 bias in the C operand of the x-projection MFMA.
  // D reg r of mfma1 is unit 8q+r; mfma2 is unit 8q+4+r.
  f32x4 cb1, cb2;
#pragma unroll
  for (int r = 0; r < 4; ++r) {
    int m1 = 8 * q + r, m2 = 8 * q + 4 + r;
    cb1[r] = b_ih[m1] + b_hh[m1];
    cb2[r] = b_ih[m2] + b_hh[m2];
  }

  // Initial B fragment from h_init: B[k=8q+i][n=lo4]
  half8 bfrag;
#pragma unroll
  for (int i = 0; i < 8; ++i)
    bfrag[i] = (_Float16)h_init[(size_t)bg * HSZ + 8 * q + i];

  // xfrag quads (rotating x4 to space register reuse): B[k][n] with
  // B[0][n] = (f16)x_n, everything else zero. Only q==0 lanes hold k=0.
  const unsigned q0m = (q == 0) ? 0xFFFFu : 0u;
  uint4v xfi0 = {0u, 0u, 0u, 0u}, xfi1 = {0u, 0u, 0u, 0u};
  uint4v xfi2 = {0u, 0u, 0u, 0u}, xfi3 = {0u, 0u, 0u, 0u};

  // Final-step f32 MFMA outputs, live across the loop for the epilogue.
  f32x4 d1g = {0.f, 0.f, 0.f, 0.f};
  f32x4 d2g = {0.f, 0.f, 0.f, 0.f};

  // Phase 1: convert+mask x into xfrag quad S (2 VALU).
#define PX(xv, S)                                                             \
  do {                                                                        \
    _Float16 xh_ = (_Float16)(xv);                                            \
    xfi##S[0] = (unsigned)__builtin_bit_cast(unsigned short, xh_) & q0m;      \
  } while (0)

  // Phase 2: x-projection MFMAs from quad S -> c1,c2 (independent of state).
#define PM(S, C1, C2)                                                         \
  do {                                                                        \
    half8 xf_ = __builtin_bit_cast(half8, xfi##S);                            \
    C1 = __builtin_amdgcn_mfma_f32_16x16x32_f16(Ax1, xf_, cb1, 0, 0, 0);      \
    C2 = __builtin_amdgcn_mfma_f32_16x16x32_f16(Ax2, xf_, cb2, 0, 0, 0);      \
  } while (0)

  // Recurrence step: 2 MFMA + 4 cvt_pkrtz + 4 pk_max_f16.
#define RSTEP(C1, C2)                                                         \
  do {                                                                        \
    f32x4 d1 = __builtin_amdgcn_mfma_f32_16x16x32_f16(A1, bfrag, C1, 0, 0, 0);\
    f32x4 d2 = __builtin_amdgcn_mfma_f32_16x16x32_f16(A2, bfrag, C2, 0, 0, 0);\
    d1g = d1;                                                                 \
    d2g = d2;                                                                 \
    union { fp16x2 h2[4]; half8 h8; } cv;                                     \
    cv.h2[0] = relu_pk(__builtin_amdgcn_cvt_pkrtz(d1[0], d1[1])); /* 8q+0,1 */\
    cv.h2[1] = relu_pk(__builtin_amdgcn_cvt_pkrtz(d1[2], d1[3])); /* 8q+2,3 */\
    cv.h2[2] = relu_pk(__builtin_amdgcn_cvt_pkrtz(d2[0], d2[1])); /* 8q+4,5 */\
    cv.h2[3] = relu_pk(__builtin_amdgcn_cvt_pkrtz(d2[2], d2[3])); /* 8q+6,7 */\
    bfrag = cv.h8;                                                            \
  } while (0)

  // x feed: lane reads its batch's row; quads 4x redundant (L1 absorbs).
  // 2-deep float4 rotation = 8-step prefetch distance.
  const float4* xr = (const float4*)(x + (size_t)bg * (size_t)T);
  const int last = T / 4 - 1;
  float4 xa = xr[0], xb = xr[1];

  f32x4 c10, c20, c11, c21, c12, c22, c13, c23;

#pragma unroll 1
  for (int t = 0; t < T; t += 8) {
    int i0 = (t >> 2) + 2; if (i0 > last) i0 = last;
    int i1 = (t >> 2) + 3; if (i1 > last) i1 = last;
    float4 na = xr[i0];
    float4 nb = xr[i1];

    // Prep 4 steps: cvt/and batch first (RAW gap to the mfmas), then 8
    // independent x-MFMAs that fill the recurrence-stall window.
    PX(xa.x, 0); PX(xa.y, 1); PX(xa.z, 2); PX(xa.w, 3);
    PM(0, c10, c20); PM(1, c11, c21); PM(2, c12, c22); PM(3, c13, c23);
    RSTEP(c10, c20); RSTEP(c11, c21); RSTEP(c12, c22); RSTEP(c13, c23);

    PX(xb.x, 0); PX(xb.y, 1); PX(xb.z, 2); PX(xb.w, 3);
    PM(0, c10, c20); PM(1, c11, c21); PM(2, c12, c22); PM(3, c13, c23);
    RSTEP(c10, c20); RSTEP(c11, c21); RSTEP(c12, c22); RSTEP(c13, c23);

    xa = na; xb = nb;
  }

  // out[bg] = sum_u relu(d[u])*W_reg[u] + b_reg; lane (q,n) holds units
  // 8q+r (d1g) and 8q+4+r (d2g) in f32. Reduce across quads.
  float v = 0.f;
#pragma unroll
  for (int r = 0; r < 4; ++r) {
    v = fmaf(fmaxf(d1g[r], 0.f), W_reg[8 * q + r], v);
    v = fmaf(fmaxf(d2g[r], 0.f), W_reg[8 * q + 4 + r], v);
  }
  v += __shfl_xor(v, 16, 64);
  v += __shfl_xor(v, 32, 64);
  if (q == 0) out[bg] = v + b_reg[0];
}

extern "C" void kernel_launch(void* const* d_in, const int* in_sizes, int n_in,
                              void* d_out, int out_size, void* d_ws, size_t ws_size,
                              hipStream_t stream) {
  const float* x      = (const float*)d_in[0];
  const float* h_init = (const float*)d_in[1];
  const float* W_ih   = (const float*)d_in[2];
  const float* W_hh   = (const float*)d_in[3];
  const float* b_ih   = (const float*)d_in[4];
  const float* b_hh   = (const float*)d_in[5];
  const float* W_reg  = (const float*)d_in[6];
  const float* b_reg  = (const float*)d_in[7];
  float* out = (float*)d_out;

  const int B = in_sizes[1] / HSZ;   // 4096
  const int T = in_sizes[0] / B;     // 4096
  const int grid = B / 16;           // 16 batches per wave/block

  rnn_reg_kernel<<<dim3(grid), dim3(64), 0, stream>>>(
      x, h_init, W_ih, W_hh, b_ih, b_hh, W_reg, b_reg, out, T);
}

// Round 3
// 462.514 us; speedup vs baseline: 1.0404x; 1.0404x over previous
//
#include <hip/hip_runtime.h>

// Elman RNN (relu), B=4096 T=4096 H=32, fp32 in/out.
// h_new[j] = relu( sum_k W_hh[j,k] h[k] + x*W_ih[j] + b_ih[j]+b_hh[j] )
//
// R12: occupancy attack. R11 taught: VALU-busy + MFMA-busy per step is
// conserved under VALU<->MFMA offload (~155 cy); 16x16x32 MFMA = ~16 cy of
// matrix pipe per SIMD. The old config ran 1 wave/CU: 3 of 4 SIMDs idle and
// ZERO co-resident waves to fill the lone wave's dependency bubbles
// (~6-9 cy/instr effective vs 2 cy issue width). This round: 2 batches per
// wave -> 2048 single-wave blocks = 8 waves/CU = 2 waves/SIMD. MFMA columns
// 2..15 are don't-care (matrix pipe was 14% busy; waste is free). Per-wave
// instruction stream identical to R10 (best: 380us); waves interleave into
// each other's stall windows.
//
// Step math (R10 structure, reverted from R11's x-MFMA):
//   C-build: 4x v_pk_fma_f32; relu AFTER f16 pack (4 cvt_pkrtz + 4
//   v_pk_max_f16, bit-identical). Final-step f32 d kept for exact epilogue.
// MFMA mapping: A1 row m -> unit u1(m)=8*(m>>2)+(m&3); A2 -> u1(m)+4.
// Lane (n=lane&15, quad q) exits with units 8q..8q+7 = next B fragment.

#define HSZ 32

typedef _Float16 half8 __attribute__((ext_vector_type(8)));
typedef _Float16 h2n __attribute__((ext_vector_type(2)));
typedef __fp16 fp16x2 __attribute__((ext_vector_type(2)));
typedef float f32x4 __attribute__((ext_vector_type(4)));
typedef float f32x2 __attribute__((ext_vector_type(2)));

// relu on a packed f16 pair: v_pk_max_f16 with inline 0.
static __device__ __forceinline__ fp16x2 relu_pk(fp16x2 a) {
  union {
    fp16x2 r;
    h2n n;
  } u;
  u.r = a;
  h2n z = {(_Float16)0.f, (_Float16)0.f};
  u.n = __builtin_elementwise_max(u.n, z);
  return u.r;
}

__global__ __attribute__((amdgpu_flat_work_group_size(64, 64),
                          amdgpu_waves_per_eu(2)))
void rnn_reg_kernel(
    const float* __restrict__ x, const float* __restrict__ h_init,
    const float* __restrict__ W_ih, const float* __restrict__ W_hh,
    const float* __restrict__ b_ih, const float* __restrict__ b_hh,
    const float* __restrict__ W_reg, const float* __restrict__ b_reg,
    float* __restrict__ out, int T) {
  const int lane = threadIdx.x;             // 0..63
  const int lo4  = lane & 15;               // MFMA column n / A row m
  const int q    = lane >> 4;               // quad 0..3
  // 2 real batches per wave, in columns 0 and 1. Other columns clamp to
  // batch 1's row (valid memory, don't-care results).
  const int bg   = blockIdx.x * 2 + (lo4 < 2 ? lo4 : 1);

  // Permuted A rows: row m of A1 is W_hh[u1(m)], row m of A2 is W_hh[u1(m)+4]
  const int u1m = 8 * (lo4 >> 2) + (lo4 & 3);
  half8 A1, A2;
#pragma unroll
  for (int j = 0; j < 8; ++j) {
    A1[j] = (_Float16)W_hh[u1m * HSZ + 8 * q + j];          // v_cvt_f16_f32 RNE
    A2[j] = (_Float16)W_hh[(u1m + 4) * HSZ + 8 * q + j];
  }

  // C-build constants as f32 pairs for v_pk_fma_f32.
  // D1 reg r is unit 8q+r, D2 reg r is unit 8q+4+r.
  const int m0 = 8 * q;
  f32x2 wih1a = {W_ih[m0 + 0], W_ih[m0 + 1]};
  f32x2 wih1b = {W_ih[m0 + 2], W_ih[m0 + 3]};
  f32x2 wih2a = {W_ih[m0 + 4], W_ih[m0 + 5]};
  f32x2 wih2b = {W_ih[m0 + 6], W_ih[m0 + 7]};
  f32x2 bia1a = {b_ih[m0 + 0] + b_hh[m0 + 0], b_ih[m0 + 1] + b_hh[m0 + 1]};
  f32x2 bia1b = {b_ih[m0 + 2] + b_hh[m0 + 2], b_ih[m0 + 3] + b_hh[m0 + 3]};
  f32x2 bia2a = {b_ih[m0 + 4] + b_hh[m0 + 4], b_ih[m0 + 5] + b_hh[m0 + 5]};
  f32x2 bia2b = {b_ih[m0 + 6] + b_hh[m0 + 6], b_ih[m0 + 7] + b_hh[m0 + 7]};

  // Initial B fragment from h_init: B[k=8q+i][n=lo4]
  half8 bfrag;
#pragma unroll
  for (int i = 0; i < 8; ++i)
    bfrag[i] = (_Float16)h_init[(size_t)bg * HSZ + 8 * q + i];

  // Final-step f32 MFMA outputs, live across the loop for the epilogue
  // (bit-identical output vs computing from the f16 state).
  f32x4 d1g = {0.f, 0.f, 0.f, 0.f};
  f32x4 d2g = {0.f, 0.f, 0.f, 0.f};

#define STEP(xv)                                                              \
  do {                                                                        \
    f32x2 xx = {(xv), (xv)};                                                  \
    f32x2 p0 = __builtin_elementwise_fma(wih1a, xx, bia1a);                   \
    f32x2 p1 = __builtin_elementwise_fma(wih1b, xx, bia1b);                   \
    f32x2 p2 = __builtin_elementwise_fma(wih2a, xx, bia2a);                   \
    f32x2 p3 = __builtin_elementwise_fma(wih2b, xx, bia2b);                   \
    f32x4 c1 = __builtin_shufflevector(p0, p1, 0, 1, 2, 3);                   \
    f32x4 c2 = __builtin_shufflevector(p2, p3, 0, 1, 2, 3);                   \
    f32x4 d1 = __builtin_amdgcn_mfma_f32_16x16x32_f16(A1, bfrag, c1, 0, 0, 0);\
    f32x4 d2 = __builtin_amdgcn_mfma_f32_16x16x32_f16(A2, bfrag, c2, 0, 0, 0);\
    d1g = d1;                                                                 \
    d2g = d2;                                                                 \
    union { fp16x2 h2[4]; half8 h8; } cv;                                     \
    cv.h2[0] = relu_pk(__builtin_amdgcn_cvt_pkrtz(d1[0], d1[1])); /* 8q+0,1 */\
    cv.h2[1] = relu_pk(__builtin_amdgcn_cvt_pkrtz(d1[2], d1[3])); /* 8q+2,3 */\
    cv.h2[2] = relu_pk(__builtin_amdgcn_cvt_pkrtz(d2[0], d2[1])); /* 8q+4,5 */\
    cv.h2[3] = relu_pk(__builtin_amdgcn_cvt_pkrtz(d2[2], d2[3])); /* 8q+6,7 */\
    bfrag = cv.h8;                                                            \
  } while (0)

  // x feed: lane reads its (clamped) batch's row. Most lanes share the same
  // address -> broadcast-coalesced; L1 absorbs the redundancy.
  // 2-deep float4 rotation = 8-step prefetch distance.
  const float4* xr = (const float4*)(x + (size_t)bg * (size_t)T);
  const int last = T / 4 - 1;
  float4 xa = xr[0], xb = xr[1];

#pragma unroll 1
  for (int t = 0; t < T; t += 8) {
    int i0 = (t >> 2) + 2; if (i0 > last) i0 = last;
    int i1 = (t >> 2) + 3; if (i1 > last) i1 = last;
    float4 na = xr[i0];
    float4 nb = xr[i1];
    STEP(xa.x); STEP(xa.y); STEP(xa.z); STEP(xa.w);
    STEP(xb.x); STEP(xb.y); STEP(xb.z); STEP(xb.w);
    xa = na; xb = nb;
  }

  // out[bg] = sum_u relu(d[u])*W_reg[u] + b_reg; lane (q,n) holds units
  // 8q+r (d1g) and 8q+4+r (d2g) in f32. Reduce across quads; only columns
  // 0,1 are real batches.
  float v = 0.f;
#pragma unroll
  for (int r = 0; r < 4; ++r) {
    v = fmaf(fmaxf(d1g[r], 0.f), W_reg[8 * q + r], v);
    v = fmaf(fmaxf(d2g[r], 0.f), W_reg[8 * q + 4 + r], v);
  }
  v += __shfl_xor(v, 16, 64);
  v += __shfl_xor(v, 32, 64);
  if (q == 0 && lo4 < 2) out[blockIdx.x * 2 + lo4] = v + b_reg[0];
}

extern "C" void kernel_launch(void* const* d_in, const int* in_sizes, int n_in,
                              void* d_out, int out_size, void* d_ws, size_t ws_size,
                              hipStream_t stream) {
  const float* x      = (const float*)d_in[0];
  const float* h_init = (const float*)d_in[1];
  const float* W_ih   = (const float*)d_in[2];
  const float* W_hh   = (const float*)d_in[3];
  const float* b_ih   = (const float*)d_in[4];
  const float* b_hh   = (const float*)d_in[5];
  const float* W_reg  = (const float*)d_in[6];
  const float* b_reg  = (const float*)d_in[7];
  float* out = (float*)d_out;

  const int B = in_sizes[1] / HSZ;   // 4096
  const int T = in_sizes[0] / B;     // 4096
  const int grid = B / 2;            // 2 batches per wave/block -> 2 waves/SIMD

  rnn_reg_kernel<<<dim3(grid), dim3(64), 0, stream>>>(
      x, h_init, W_ih, W_hh, b_ih, b_hh, W_reg, b_reg, out, T);
}

// Round 4
// 445.373 us; speedup vs baseline: 1.0805x; 1.0385x over previous
//
#include <hip/hip_runtime.h>

// Elman RNN (relu), B=4096 T=4096 H=32, fp32 in/out.
// h_new[j] = relu( sum_k W_hh[j,k] h[k] + x*W_ih[j] + b_ih[j]+b_hh[j] )
//
// R13: 2 waves/SIMD at FULL bpw=16. R12 measured: one STEP stream = ~67 cy
// VALU pipe/step; at 2 waves/SIMD wall/wave-step = 133 cy (vs 223 cy for a
// lone wave — sibling wave fills the mfma->cvt chain stalls). R12's mistake
// was paying 8x in batches/wave for that. This round: 512-thread blocks
// (8 waves) -> waves round-robin onto 4 SIMDs = exactly 2/SIMD, each wave
// keeps all 16 MFMA columns as real batches. Grid = 4096/128 = 32 blocks
// (32 CUs; per measured model beats 256 CUs at 1 wave/SIMD: ~227us pred).
// Also: last-8-step peel — d1g/d2g (final-step f32 MFMA out, needed for the
// bit-exact epilogue) is only saved in the peeled final step, removing the
// ~8 v_mov/step live-copy from the other T-8 steps.
//
// Step math (R10 structure): C-build 4x v_pk_fma_f32; relu AFTER f16 pack
// (4 cvt_pkrtz + 4 v_pk_max_f16, bit-identical).
// MFMA mapping: A1 row m -> unit u1(m)=8*(m>>2)+(m&3); A2 -> u1(m)+4.
// Lane (n=lane&15, quad q) exits with units 8q..8q+7 = next B fragment.

#define HSZ 32

typedef _Float16 half8 __attribute__((ext_vector_type(8)));
typedef _Float16 h2n __attribute__((ext_vector_type(2)));
typedef __fp16 fp16x2 __attribute__((ext_vector_type(2)));
typedef float f32x4 __attribute__((ext_vector_type(4)));
typedef float f32x2 __attribute__((ext_vector_type(2)));

// relu on a packed f16 pair: v_pk_max_f16 with inline 0.
static __device__ __forceinline__ fp16x2 relu_pk(fp16x2 a) {
  union {
    fp16x2 r;
    h2n n;
  } u;
  u.r = a;
  h2n z = {(_Float16)0.f, (_Float16)0.f};
  u.n = __builtin_elementwise_max(u.n, z);
  return u.r;
}

__global__ __attribute__((amdgpu_flat_work_group_size(512, 512)))
void rnn_reg_kernel(
    const float* __restrict__ x, const float* __restrict__ h_init,
    const float* __restrict__ W_ih, const float* __restrict__ W_hh,
    const float* __restrict__ b_ih, const float* __restrict__ b_hh,
    const float* __restrict__ W_reg, const float* __restrict__ b_reg,
    float* __restrict__ out, int T) {
  const int lane = threadIdx.x & 63;        // 0..63 within wave
  const int wid  = threadIdx.x >> 6;        // wave 0..7 -> SIMD wid&3
  const int lo4  = lane & 15;               // batch column n / A row m
  const int q    = lane >> 4;               // quad 0..3
  const int bg   = blockIdx.x * 128 + wid * 16 + lo4;  // this lane's batch

  // Permuted A rows: row m of A1 is W_hh[u1(m)], row m of A2 is W_hh[u1(m)+4]
  const int u1m = 8 * (lo4 >> 2) + (lo4 & 3);
  half8 A1, A2;
#pragma unroll
  for (int j = 0; j < 8; ++j) {
    A1[j] = (_Float16)W_hh[u1m * HSZ + 8 * q + j];          // v_cvt_f16_f32 RNE
    A2[j] = (_Float16)W_hh[(u1m + 4) * HSZ + 8 * q + j];
  }

  // C-build constants as f32 pairs for v_pk_fma_f32.
  // D1 reg r is unit 8q+r, D2 reg r is unit 8q+4+r.
  const int m0 = 8 * q;
  f32x2 wih1a = {W_ih[m0 + 0], W_ih[m0 + 1]};
  f32x2 wih1b = {W_ih[m0 + 2], W_ih[m0 + 3]};
  f32x2 wih2a = {W_ih[m0 + 4], W_ih[m0 + 5]};
  f32x2 wih2b = {W_ih[m0 + 6], W_ih[m0 + 7]};
  f32x2 bia1a = {b_ih[m0 + 0] + b_hh[m0 + 0], b_ih[m0 + 1] + b_hh[m0 + 1]};
  f32x2 bia1b = {b_ih[m0 + 2] + b_hh[m0 + 2], b_ih[m0 + 3] + b_hh[m0 + 3]};
  f32x2 bia2a = {b_ih[m0 + 4] + b_hh[m0 + 4], b_ih[m0 + 5] + b_hh[m0 + 5]};
  f32x2 bia2b = {b_ih[m0 + 6] + b_hh[m0 + 6], b_ih[m0 + 7] + b_hh[m0 + 7]};

  // Initial B fragment from h_init: B[k=8q+i][n=lo4]
  half8 bfrag;
#pragma unroll
  for (int i = 0; i < 8; ++i)
    bfrag[i] = (_Float16)h_init[(size_t)bg * HSZ + 8 * q + i];

  // Final-step f32 MFMA outputs (written ONLY in the peeled last step).
  f32x4 d1g = {0.f, 0.f, 0.f, 0.f};
  f32x4 d2g = {0.f, 0.f, 0.f, 0.f};

  // Hot-loop step: no d live-copy.
#define STEP(xv)                                                              \
  do {                                                                        \
    f32x2 xx = {(xv), (xv)};                                                  \
    f32x2 p0 = __builtin_elementwise_fma(wih1a, xx, bia1a);                   \
    f32x2 p1 = __builtin_elementwise_fma(wih1b, xx, bia1b);                   \
    f32x2 p2 = __builtin_elementwise_fma(wih2a, xx, bia2a);                   \
    f32x2 p3 = __builtin_elementwise_fma(wih2b, xx, bia2b);                   \
    f32x4 c1 = __builtin_shufflevector(p0, p1, 0, 1, 2, 3);                   \
    f32x4 c2 = __builtin_shufflevector(p2, p3, 0, 1, 2, 3);                   \
    f32x4 d1 = __builtin_amdgcn_mfma_f32_16x16x32_f16(A1, bfrag, c1, 0, 0, 0);\
    f32x4 d2 = __builtin_amdgcn_mfma_f32_16x16x32_f16(A2, bfrag, c2, 0, 0, 0);\
    union { fp16x2 h2[4]; half8 h8; } cv;                                     \
    cv.h2[0] = relu_pk(__builtin_amdgcn_cvt_pkrtz(d1[0], d1[1])); /* 8q+0,1 */\
    cv.h2[1] = relu_pk(__builtin_amdgcn_cvt_pkrtz(d1[2], d1[3])); /* 8q+2,3 */\
    cv.h2[2] = relu_pk(__builtin_amdgcn_cvt_pkrtz(d2[0], d2[1])); /* 8q+4,5 */\
    cv.h2[3] = relu_pk(__builtin_amdgcn_cvt_pkrtz(d2[2], d2[3])); /* 8q+6,7 */\
    bfrag = cv.h8;                                                            \
  } while (0)

  // Final step: save the f32 d for the bit-exact epilogue.
#define STEPD(xv)                                                             \
  do {                                                                        \
    f32x2 xx = {(xv), (xv)};                                                  \
    f32x2 p0 = __builtin_elementwise_fma(wih1a, xx, bia1a);                   \
    f32x2 p1 = __builtin_elementwise_fma(wih1b, xx, bia1b);                   \
    f32x2 p2 = __builtin_elementwise_fma(wih2a, xx, bia2a);                   \
    f32x2 p3 = __builtin_elementwise_fma(wih2b, xx, bia2b);                   \
    f32x4 c1 = __builtin_shufflevector(p0, p1, 0, 1, 2, 3);                   \
    f32x4 c2 = __builtin_shufflevector(p2, p3, 0, 1, 2, 3);                   \
    d1g = __builtin_amdgcn_mfma_f32_16x16x32_f16(A1, bfrag, c1, 0, 0, 0);     \
    d2g = __builtin_amdgcn_mfma_f32_16x16x32_f16(A2, bfrag, c2, 0, 0, 0);     \
  } while (0)

  // x feed: lane reads its batch's row; quads 4x redundant (L1 absorbs).
  // 2-deep float4 rotation = 8-step prefetch distance.
  const float4* xr = (const float4*)(x + (size_t)bg * (size_t)T);
  const int last = T / 4 - 1;
  float4 xa = xr[0], xb = xr[1];

#pragma unroll 1
  for (int t = 0; t < T - 8; t += 8) {
    int i0 = (t >> 2) + 2; if (i0 > last) i0 = last;
    int i1 = (t >> 2) + 3; if (i1 > last) i1 = last;
    float4 na = xr[i0];
    float4 nb = xr[i1];
    STEP(xa.x); STEP(xa.y); STEP(xa.z); STEP(xa.w);
    STEP(xb.x); STEP(xb.y); STEP(xb.z); STEP(xb.w);
    xa = na; xb = nb;
  }

  // Peeled last 8 steps: xa = x[T-8..T-5], xb = x[T-4..T-1].
  STEP(xa.x); STEP(xa.y); STEP(xa.z); STEP(xa.w);
  STEP(xb.x); STEP(xb.y); STEP(xb.z);
  STEPD(xb.w);

  // out[bg] = sum_u relu(d[u])*W_reg[u] + b_reg; lane (q,n) holds units
  // 8q+r (d1g) and 8q+4+r (d2g) in f32. Reduce across quads.
  float v = 0.f;
#pragma unroll
  for (int r = 0; r < 4; ++r) {
    v = fmaf(fmaxf(d1g[r], 0.f), W_reg[8 * q + r], v);
    v = fmaf(fmaxf(d2g[r], 0.f), W_reg[8 * q + 4 + r], v);
  }
  v += __shfl_xor(v, 16, 64);
  v += __shfl_xor(v, 32, 64);
  if (q == 0) out[bg] = v + b_reg[0];
}

extern "C" void kernel_launch(void* const* d_in, const int* in_sizes, int n_in,
                              void* d_out, int out_size, void* d_ws, size_t ws_size,
                              hipStream_t stream) {
  const float* x      = (const float*)d_in[0];
  const float* h_init = (const float*)d_in[1];
  const float* W_ih   = (const float*)d_in[2];
  const float* W_hh   = (const float*)d_in[3];
  const float* b_ih   = (const float*)d_in[4];
  const float* b_hh   = (const float*)d_in[5];
  const float* W_reg  = (const float*)d_in[6];
  const float* b_reg  = (const float*)d_in[7];
  float* out = (float*)d_out;

  const int B = in_sizes[1] / HSZ;   // 4096
  const int T = in_sizes[0] / B;     // 4096
  const int grid = B / 128;          // 8 waves/block x 16 batches/wave

  rnn_reg_kernel<<<dim3(grid), dim3(512), 0, stream>>>(
      x, h_init, W_ih, W_hh, b_ih, b_hh, W_reg, b_reg, out, T);
}